// Round 1
// baseline (649.066 us; speedup 1.0000x reference)
//
#include <hip/hip_runtime.h>
#include <hip/hip_bf16.h>

// Air3D CNF forward: traj (batch-independent ODE, computed ONCE) + bf16-MFMA decoder.
// ws layout: pw0[128*512] pw1[512*512] pw2[512*512] pw3[512*16] (ushort bf16) + traj[101*10] f32

#define B_TOTAL 65536
#define MTILE   64

typedef short bf16x8 __attribute__((ext_vector_type(8)));
typedef float f32x4  __attribute__((ext_vector_type(4)));

__device__ __forceinline__ float tanh_fast(float x) {
  float xc = fminf(fmaxf(x, -9.0f), 9.0f);
  float e = __expf(2.0f * xc);
  return __fdividef(e - 1.0f, e + 1.0f);
}

__device__ __forceinline__ unsigned short f2bf(float f) {
  union { float f; unsigned u; } v; v.f = f;
  unsigned r = v.u + 0x7FFFu + ((v.u >> 16) & 1u);   // RNE to bf16
  return (unsigned short)(r >> 16);
}

// ---------------- weight packing into MFMA B-fragment order ----------------
// frag index f = ntile*(K/32)+kc; element: lane l, slot j -> W[kc*32 + (l>>4)*8 + j][ntile*16 + (l&15)]
// (k-slot map g*8+j matches the LDS A-read map below, so any HW k permutation cancels.)
__global__ void pack_kernel(const float* __restrict__ w, unsigned short* __restrict__ pw,
                            int K_real, int N_real, int KC, int total) {
  int idx = blockIdx.x * 256 + threadIdx.x;
  if (idx >= total) return;
  int j = idx & 7;
  int l = (idx >> 3) & 63;
  int rest = idx >> 9;
  int kc = rest % KC;
  int ntg = rest / KC;
  int k = kc * 32 + ((l >> 4) << 3) + j;
  int n = ntg * 16 + (l & 15);
  float v = (k < K_real && n < N_real) ? w[k * N_real + n] : 0.0f;
  pw[idx] = f2bf(v);
}

// ---------------- trajectory: single block, 128 threads, fp32 ----------------
__global__ __launch_bounds__(128) void traj_kernel(
    const float* __restrict__ w0, const float* __restrict__ b0,
    const float* __restrict__ w1, const float* __restrict__ b1,
    const float* __restrict__ w2, const float* __restrict__ b2,
    float* __restrict__ traj) {
  __shared__ __align__(16) float ain[16];
  __shared__ __align__(16) float h1[128];
  __shared__ __align__(16) float h2[128];
  __shared__ __align__(16) float kst[16];
  const int tid = threadIdx.x;
  const float dtau = 1.0f / 100.0f;

  // per-thread weight columns in registers
  float w0c[11], w1c[128];
  float b0j = b0[tid], b1j = b1[tid];
#pragma unroll
  for (int i = 0; i < 11; i++) w0c[i] = w0[i * 128 + tid];
#pragma unroll
  for (int i = 0; i < 128; i++) w1c[i] = w1[i * 128 + tid];

  const int kk = tid >> 3, p = tid & 7;   // L3: 8 threads per output, 10 outputs -> tid<80
  float w2r[16];
  float b2k = 0.0f;
  if (tid < 80) {
#pragma unroll
    for (int ii = 0; ii < 16; ii++) w2r[ii] = w2[(p * 16 + ii) * 10 + kk];
    if (p == 0) b2k = b2[kk];
  }

  float a_j = 0.0f;
  if (tid < 10) traj[tid] = 0.0f;
  float k1j = 0.f, k2j = 0.f, k3j = 0.f;

  auto eval = [&](float tval) {
    // L1: 11 -> 128
    float pre = b0j;
#pragma unroll
    for (int i = 0; i < 10; i++) pre = fmaf(ain[i], w0c[i], pre);
    pre = fmaf(tval, w0c[10], pre);
    h1[tid] = tanh_fast(pre);
    __syncthreads();
    // L2: 128 -> 128 (broadcast LDS float4 reads, 4 accumulators)
    float ac0 = 0.f, ac1 = 0.f, ac2 = 0.f, ac3 = 0.f;
    const float4* h1v = (const float4*)h1;
#pragma unroll
    for (int i = 0; i < 32; i++) {
      float4 hv = h1v[i];
      ac0 = fmaf(hv.x, w1c[4 * i + 0], ac0);
      ac1 = fmaf(hv.y, w1c[4 * i + 1], ac1);
      ac2 = fmaf(hv.z, w1c[4 * i + 2], ac2);
      ac3 = fmaf(hv.w, w1c[4 * i + 3], ac3);
    }
    h2[tid] = tanh_fast(b1j + ((ac0 + ac1) + (ac2 + ac3)));
    __syncthreads();
    // L3: 128 -> 10, 8-lane partial + shuffle reduce
    if (tid < 80) {
      float part = 0.f;
#pragma unroll
      for (int ii = 0; ii < 16; ii++) part = fmaf(h2[p * 16 + ii], w2r[ii], part);
      part += __shfl_xor(part, 1);
      part += __shfl_xor(part, 2);
      part += __shfl_xor(part, 4);
      if (p == 0) kst[kk] = part + b2k;
    }
    __syncthreads();
  };

  for (int s = 0; s < 100; s++) {
    float t0 = (float)s * dtau;
    if (tid < 10) ain[tid] = a_j;
    __syncthreads();
    eval(t0);
    if (tid < 10) { k1j = kst[tid]; ain[tid] = fmaf(0.5f * dtau, k1j, a_j); }
    __syncthreads();
    eval(t0 + 0.5f * dtau);
    if (tid < 10) { k2j = kst[tid]; ain[tid] = fmaf(0.5f * dtau, k2j, a_j); }
    __syncthreads();
    eval(t0 + 0.5f * dtau);
    if (tid < 10) { k3j = kst[tid]; ain[tid] = fmaf(dtau, k3j, a_j); }
    __syncthreads();
    eval(t0 + dtau);
    if (tid < 10) {
      float k4j = kst[tid];
      a_j = a_j + (dtau / 6.0f) * (k1j + 2.0f * k2j + 2.0f * k3j + k4j);
      traj[(s + 1) * 10 + tid] = a_j;
    }
  }
}

// ---------------- decoder layer: M=64 rows, wave owns 64-col N-slice ----------------
// A from swizzled LDS (ds_read_b128), B from packed global frags (coalesced 1KB/frag).
template <int KC, int SSTR, bool ACT>
__device__ __forceinline__ void layer(const char* src, const unsigned short* __restrict__ pw,
                                      const float* __restrict__ bias, char* dst,
                                      int wave, int lane) {
  f32x4 acc[4][4];
#pragma unroll
  for (int a = 0; a < 4; a++)
#pragma unroll
    for (int b = 0; b < 4; b++) acc[a][b] = f32x4{0.f, 0.f, 0.f, 0.f};

#pragma unroll
  for (int kc = 0; kc < KC; kc++) {
    bf16x8 af[4];
#pragma unroll
    for (int mt = 0; mt < 4; mt++) {
      int r = mt * 16 + (lane & 15);
      int cb = kc * 64 + ((lane >> 4) << 4);
      af[mt] = *(const bf16x8*)(src + r * SSTR + (cb ^ ((r & 7) << 4)));
    }
    bf16x8 bfr[4];
#pragma unroll
    for (int nt = 0; nt < 4; nt++) {
      int ntg = wave * 4 + nt;
      bfr[nt] = *(const bf16x8*)(pw + ((ntg * KC + kc) * 64 + lane) * 8);
    }
#pragma unroll
    for (int mt = 0; mt < 4; mt++)
#pragma unroll
      for (int nt = 0; nt < 4; nt++)
        acc[mt][nt] = __builtin_amdgcn_mfma_f32_16x16x32_bf16(af[mt], bfr[nt], acc[mt][nt], 0, 0, 0);
  }
  // epilogue: bias + tanh -> bf16 -> swizzled LDS (C/D: col=lane&15, row=(lane>>4)*4+r)
#pragma unroll
  for (int mt = 0; mt < 4; mt++) {
#pragma unroll
    for (int nt = 0; nt < 4; nt++) {
      int col = wave * 64 + nt * 16 + (lane & 15);
      float bv = bias[col];
#pragma unroll
      for (int r = 0; r < 4; r++) {
        int row = mt * 16 + ((lane >> 4) << 2) + r;
        float v = acc[mt][nt][r] + bv;
        if (ACT) v = tanh_fast(v);
        *(unsigned short*)(dst + row * 1024 + ((col * 2) ^ ((row & 7) << 4))) = f2bf(v);
      }
    }
  }
}

__global__ __launch_bounds__(512, 2) void decoder_kernel(
    const float* __restrict__ x, const float* __restrict__ tauv,
    const unsigned short* __restrict__ pw0, const float* __restrict__ db0,
    const unsigned short* __restrict__ pw1, const float* __restrict__ db1,
    const unsigned short* __restrict__ pw2, const float* __restrict__ db2,
    const unsigned short* __restrict__ pw3, const float* __restrict__ db3,
    const float* __restrict__ traj, float* __restrict__ out) {
  __shared__ char smem[131072];           // Ha 64KB (phi = first 16KB) | Hb 64KB
  char* Ha = smem;
  char* Hb = smem + 65536;
  const int tid = threadIdx.x;
  const int lane = tid & 63;
  const int wave = tid >> 6;
  const int row0 = blockIdx.x * MTILE;

  // ---- stage: Fourier features into phi (rows stride 256B, XOR-swizzled) ----
  for (int idx = tid; idx < 64 * 96; idx += 512) {
    int r = idx / 96, f = idx % 96;
    int d = f >> 5, s = f & 31;
    float xv = x[(row0 + r) * 3 + d];
    float freq = 1.0f + 0.6f * (float)(s & 15);
    float rev = xv * freq;                 // revolutions: sin(2*pi*x*f) = v_sin(x*f)
    rev = rev - floorf(rev);
    float val = (s < 16) ? __builtin_amdgcn_sinf(rev) : __builtin_amdgcn_cosf(rev);
    int cb = f * 2;
    *(unsigned short*)(Ha + r * 256 + (cb ^ ((r & 7) << 4))) = f2bf(val);
  }
  // ---- stage: alpha(tau) interp + zero pad (cols 96..127) ----
  if (tid < 64) {
    int i = row0 + tid;
    float tv = tauv[i];
    const float dtau = 1.0f / 100.0f;
    int idx = (int)floorf(tv / dtau);
    idx = min(max(idx, 0), 99);
    float ratio = (tv - (float)idx * dtau) / dtau;
#pragma unroll
    for (int j = 0; j < 10; j++) {
      float a0 = traj[idx * 10 + j], a1 = traj[idx * 10 + 10 + j];
      float al = fmaf(ratio, a1 - a0, a0);
      int cb = (96 + j) * 2;
      *(unsigned short*)(Ha + tid * 256 + (cb ^ ((tid & 7) << 4))) = f2bf(al);
    }
#pragma unroll
    for (int j = 106; j < 128; j++) {
      int cb = j * 2;
      *(unsigned short*)(Ha + tid * 256 + (cb ^ ((tid & 7) << 4))) = 0;
    }
  }
  __syncthreads();

  layer<4, 256, true>(Ha, pw0, db0, Hb, wave, lane);    // 106(pad128) -> 512
  __syncthreads();
  layer<16, 1024, true>(Hb, pw1, db1, Ha, wave, lane);  // 512 -> 512
  __syncthreads();
  layer<16, 1024, true>(Ha, pw2, db2, Hb, wave, lane);  // 512 -> 512
  __syncthreads();

  // ---- L3: 512 -> 1 via MFMA, waves 0..3 each own a 16-row m-tile ----
  float* ubuf = (float*)Ha;
  if (wave < 4) {
    f32x4 acc = {0.f, 0.f, 0.f, 0.f};
#pragma unroll
    for (int kc = 0; kc < 16; kc++) {
      int arow = wave * 16 + (lane & 15);
      int acb = kc * 64 + ((lane >> 4) << 4);
      bf16x8 af = *(const bf16x8*)(Hb + arow * 1024 + (acb ^ ((arow & 7) << 4)));
      bf16x8 bfv = *(const bf16x8*)(pw3 + (kc * 64 + lane) * 8);
      acc = __builtin_amdgcn_mfma_f32_16x16x32_bf16(af, bfv, acc, 0, 0, 0);
    }
    if ((lane & 15) == 0) {
#pragma unroll
      for (int r = 0; r < 4; r++) {
        int rr = wave * 16 + ((lane >> 4) << 2) + r;
        ubuf[rr] = acc[r];
      }
    }
  }
  __syncthreads();

  // ---- epilogue: out = lx + tau * (u + b3) ----
  if (tid < 64) {
    int i = row0 + tid;
    float x0 = x[i * 3], x1 = x[i * 3 + 1];
    float tv = tauv[i];
    float u = ubuf[tid] + db3[0];
    out[i] = sqrtf(x0 * x0 + x1 * x1) - 0.25f + tv * u;
  }
}

// ---------------- launch ----------------
extern "C" void kernel_launch(void* const* d_in, const int* in_sizes, int n_in,
                              void* d_out, int out_size, void* d_ws, size_t ws_size,
                              hipStream_t stream) {
  const float* x    = (const float*)d_in[0];
  const float* tauv = (const float*)d_in[1];
  const float* dw0  = (const float*)d_in[2];
  const float* db0  = (const float*)d_in[3];
  const float* dw1  = (const float*)d_in[4];
  const float* db1  = (const float*)d_in[5];
  const float* dw2  = (const float*)d_in[6];
  const float* db2  = (const float*)d_in[7];
  const float* dw3  = (const float*)d_in[8];
  const float* db3  = (const float*)d_in[9];
  const float* pnw0 = (const float*)d_in[10];
  const float* pnb0 = (const float*)d_in[11];
  const float* pnw1 = (const float*)d_in[12];
  const float* pnb1 = (const float*)d_in[13];
  const float* pnw2 = (const float*)d_in[14];
  const float* pnb2 = (const float*)d_in[15];
  float* out = (float*)d_out;

  unsigned short* pw0 = (unsigned short*)d_ws;
  unsigned short* pw1 = pw0 + 128 * 512;
  unsigned short* pw2 = pw1 + 512 * 512;
  unsigned short* pw3 = pw2 + 512 * 512;
  float* traj = (float*)(pw3 + 512 * 16);

  pack_kernel<<<(128 * 512) / 256, 256, 0, stream>>>(dw0, pw0, 106, 512, 4, 128 * 512);
  pack_kernel<<<(512 * 512) / 256, 256, 0, stream>>>(dw1, pw1, 512, 512, 16, 512 * 512);
  pack_kernel<<<(512 * 512) / 256, 256, 0, stream>>>(dw2, pw2, 512, 512, 16, 512 * 512);
  pack_kernel<<<(512 * 16) / 256, 256, 0, stream>>>(dw3, pw3, 512, 1, 16, 512 * 16);
  traj_kernel<<<1, 128, 0, stream>>>(pnw0, pnb0, pnw1, pnb1, pnw2, pnb2, traj);
  decoder_kernel<<<B_TOTAL / MTILE, 512, 0, stream>>>(x, tauv, pw0, db0, pw1, db1,
                                                      pw2, db2, pw3, db3, traj, out);
}

// Round 2
// 330.653 us; speedup vs baseline: 1.9630x; 1.9630x over previous
//
#include <hip/hip_runtime.h>
#include <hip/hip_bf16.h>

// Air3D CNF forward: traj (batch-independent ODE, computed ONCE, RK4-25 + cubic
// Hermite dense output onto the 101-point grid) + bf16-MFMA decoder.
// ws layout: pw0[128*512] pw1[512*512] pw2[512*512] pw3[512*16] (ushort bf16) + traj[101*10] f32

#define B_TOTAL 65536
#define MTILE   64

typedef short bf16x8 __attribute__((ext_vector_type(8)));
typedef float f32x4  __attribute__((ext_vector_type(4)));

__device__ __forceinline__ float tanh_fast(float x) {
  float xc = fminf(fmaxf(x, -9.0f), 9.0f);
  float e = __expf(2.0f * xc);
  return __fdividef(e - 1.0f, e + 1.0f);
}

__device__ __forceinline__ unsigned short f2bf(float f) {
  union { float f; unsigned u; } v; v.f = f;
  unsigned r = v.u + 0x7FFFu + ((v.u >> 16) & 1u);   // RNE to bf16
  return (unsigned short)(r >> 16);
}

// ---------------- weight packing into MFMA B-fragment order ----------------
// frag index f = ntile*(K/32)+kc; element: lane l, slot j -> W[kc*32 + (l>>4)*8 + j][ntile*16 + (l&15)]
// (k-slot map g*8+j matches the LDS A-read map below, so any HW k permutation cancels.)
__global__ void pack_kernel(const float* __restrict__ w, unsigned short* __restrict__ pw,
                            int K_real, int N_real, int KC, int total) {
  int idx = blockIdx.x * 256 + threadIdx.x;
  if (idx >= total) return;
  int j = idx & 7;
  int l = (idx >> 3) & 63;
  int rest = idx >> 9;
  int kc = rest % KC;
  int ntg = rest / KC;
  int k = kc * 32 + ((l >> 4) << 3) + j;
  int n = ntg * 16 + (l & 15);
  float v = (k < K_real && n < N_real) ? w[k * N_real + n] : 0.0f;
  pw[idx] = f2bf(v);
}

// ---------------- trajectory: single block, 128 threads, fp32 ----------------
// RK4 with h=0.04 (25 steps) instead of reference's h=0.01 (difference ~3e-6),
// interior grid points (spacing 0.01) via cubic Hermite using k1 endpoints.
__global__ __launch_bounds__(128) void traj_kernel(
    const float* __restrict__ w0, const float* __restrict__ b0,
    const float* __restrict__ w1, const float* __restrict__ b1,
    const float* __restrict__ w2, const float* __restrict__ b2,
    float* __restrict__ traj) {
  __shared__ __align__(16) float ain[16];
  __shared__ __align__(16) float h1[128];
  __shared__ __align__(16) float h2[128];
  __shared__ __align__(16) float kst[16];
  const int tid = threadIdx.x;
  const float H = 0.04f;        // 4 * reference dtau

  // per-thread weight columns in registers
  float w0c[11], w1c[128];
  float b0j = b0[tid], b1j = b1[tid];
#pragma unroll
  for (int i = 0; i < 11; i++) w0c[i] = w0[i * 128 + tid];
#pragma unroll
  for (int i = 0; i < 128; i++) w1c[i] = w1[i * 128 + tid];

  const int kk = tid >> 3, p = tid & 7;   // L3: 8 threads per output, 10 outputs -> tid<80
  float w2r[16];
  float b2k = 0.0f;
  if (tid < 80) {
#pragma unroll
    for (int ii = 0; ii < 16; ii++) w2r[ii] = w2[(p * 16 + ii) * 10 + kk];
    if (p == 0) b2k = b2[kk];
  }

  float a_j = 0.0f;
  float k1j = 0.f, k2j = 0.f, k3j = 0.f;
  float a_ps = 0.f, k1p = 0.f;   // previous step start-state and its f, for Hermite

  auto eval = [&](float tval) {
    // L1: 11 -> 128
    float pre = b0j;
#pragma unroll
    for (int i = 0; i < 10; i++) pre = fmaf(ain[i], w0c[i], pre);
    pre = fmaf(tval, w0c[10], pre);
    h1[tid] = tanh_fast(pre);
    __syncthreads();
    // L2: 128 -> 128 (broadcast LDS float4 reads, 4 accumulators)
    float ac0 = 0.f, ac1 = 0.f, ac2 = 0.f, ac3 = 0.f;
    const float4* h1v = (const float4*)h1;
#pragma unroll
    for (int i = 0; i < 32; i++) {
      float4 hv = h1v[i];
      ac0 = fmaf(hv.x, w1c[4 * i + 0], ac0);
      ac1 = fmaf(hv.y, w1c[4 * i + 1], ac1);
      ac2 = fmaf(hv.z, w1c[4 * i + 2], ac2);
      ac3 = fmaf(hv.w, w1c[4 * i + 3], ac3);
    }
    h2[tid] = tanh_fast(b1j + ((ac0 + ac1) + (ac2 + ac3)));
    __syncthreads();
    // L3: 128 -> 10, 8-lane partial + shuffle reduce
    if (tid < 80) {
      float part = 0.f;
#pragma unroll
      for (int ii = 0; ii < 16; ii++) part = fmaf(h2[p * 16 + ii], w2r[ii], part);
      part += __shfl_xor(part, 1);
      part += __shfl_xor(part, 2);
      part += __shfl_xor(part, 4);
      if (p == 0) kst[kk] = part + b2k;
    }
    __syncthreads();
  };

  // cubic Hermite dense output for one h-interval (grid base g), lanes tid<10
  auto dense = [&](int g, float a0, float f0, float a1, float f1) {
    // theta=0.25 / 0.5 / 0.75 ; h10/h11 scaled by H=0.04
    traj[(g + 1) * 10 + tid] =
        0.84375f * a0 + 0.0056250f * f0 + 0.15625f * a1 - 0.0018750f * f1;
    traj[(g + 2) * 10 + tid] =
        0.5f * a0 + 0.005f * f0 + 0.5f * a1 - 0.005f * f1;
    traj[(g + 3) * 10 + tid] =
        0.15625f * a0 + 0.0018750f * f0 + 0.84375f * a1 - 0.0056250f * f1;
  };

  for (int s = 0; s < 25; s++) {
    float t0 = (float)s * H;
    if (tid < 10) ain[tid] = a_j;
    __syncthreads();
    eval(t0);                              // k1 = f(t0, a)
    if (tid < 10) {
      k1j = kst[tid];
      traj[(4 * s) * 10 + tid] = a_j;      // exact grid value at step start
      if (s > 0) dense(4 * (s - 1), a_ps, k1p, a_j, k1j);
      a_ps = a_j; k1p = k1j;
      ain[tid] = fmaf(0.02f, k1j, a_j);
    }
    __syncthreads();
    eval(t0 + 0.02f);                      // k2
    if (tid < 10) { k2j = kst[tid]; ain[tid] = fmaf(0.02f, k2j, a_j); }
    __syncthreads();
    eval(t0 + 0.02f);                      // k3
    if (tid < 10) { k3j = kst[tid]; ain[tid] = fmaf(0.04f, k3j, a_j); }
    __syncthreads();
    eval(t0 + 0.04f);                      // k4
    if (tid < 10) {
      float k4j = kst[tid];
      a_j = a_j + (H / 6.0f) * (k1j + 2.0f * k2j + 2.0f * k3j + k4j);
    }
  }
  // final: f(1.0, a_25) for the last interval's Hermite + grid 100
  if (tid < 10) ain[tid] = a_j;
  __syncthreads();
  eval(1.0f);
  if (tid < 10) {
    float f1 = kst[tid];
    dense(96, a_ps, k1p, a_j, f1);
    traj[100 * 10 + tid] = a_j;
  }
}

// ---------------- decoder layer: M=64 rows, wave owns 64-col N-slice ----------------
// A from swizzled LDS (ds_read_b128), B from packed global frags (coalesced 1KB/frag).
template <int KC, int SSTR, bool ACT>
__device__ __forceinline__ void layer(const char* src, const unsigned short* __restrict__ pw,
                                      const float* __restrict__ bias, char* dst,
                                      int wave, int lane) {
  f32x4 acc[4][4];
#pragma unroll
  for (int a = 0; a < 4; a++)
#pragma unroll
    for (int b = 0; b < 4; b++) acc[a][b] = f32x4{0.f, 0.f, 0.f, 0.f};

#pragma unroll
  for (int kc = 0; kc < KC; kc++) {
    bf16x8 af[4];
#pragma unroll
    for (int mt = 0; mt < 4; mt++) {
      int r = mt * 16 + (lane & 15);
      int cb = kc * 64 + ((lane >> 4) << 4);
      af[mt] = *(const bf16x8*)(src + r * SSTR + (cb ^ ((r & 7) << 4)));
    }
    bf16x8 bfr[4];
#pragma unroll
    for (int nt = 0; nt < 4; nt++) {
      int ntg = wave * 4 + nt;
      bfr[nt] = *(const bf16x8*)(pw + ((ntg * KC + kc) * 64 + lane) * 8);
    }
#pragma unroll
    for (int mt = 0; mt < 4; mt++)
#pragma unroll
      for (int nt = 0; nt < 4; nt++)
        acc[mt][nt] = __builtin_amdgcn_mfma_f32_16x16x32_bf16(af[mt], bfr[nt], acc[mt][nt], 0, 0, 0);
  }
  // epilogue: bias + tanh -> bf16 -> swizzled LDS (C/D: col=lane&15, row=(lane>>4)*4+r)
#pragma unroll
  for (int mt = 0; mt < 4; mt++) {
#pragma unroll
    for (int nt = 0; nt < 4; nt++) {
      int col = wave * 64 + nt * 16 + (lane & 15);
      float bv = bias[col];
#pragma unroll
      for (int r = 0; r < 4; r++) {
        int row = mt * 16 + ((lane >> 4) << 2) + r;
        float v = acc[mt][nt][r] + bv;
        if (ACT) v = tanh_fast(v);
        *(unsigned short*)(dst + row * 1024 + ((col * 2) ^ ((row & 7) << 4))) = f2bf(v);
      }
    }
  }
}

__global__ __launch_bounds__(512, 2) void decoder_kernel(
    const float* __restrict__ x, const float* __restrict__ tauv,
    const unsigned short* __restrict__ pw0, const float* __restrict__ db0,
    const unsigned short* __restrict__ pw1, const float* __restrict__ db1,
    const unsigned short* __restrict__ pw2, const float* __restrict__ db2,
    const unsigned short* __restrict__ pw3, const float* __restrict__ db3,
    const float* __restrict__ traj, float* __restrict__ out) {
  __shared__ char smem[131072];           // Ha 64KB (phi = first 16KB) | Hb 64KB
  char* Ha = smem;
  char* Hb = smem + 65536;
  const int tid = threadIdx.x;
  const int lane = tid & 63;
  const int wave = tid >> 6;
  const int row0 = blockIdx.x * MTILE;

  // ---- stage: Fourier features into phi (rows stride 256B, XOR-swizzled) ----
  for (int idx = tid; idx < 64 * 96; idx += 512) {
    int r = idx / 96, f = idx % 96;
    int d = f >> 5, s = f & 31;
    float xv = x[(row0 + r) * 3 + d];
    float freq = 1.0f + 0.6f * (float)(s & 15);
    float rev = xv * freq;                 // revolutions: sin(2*pi*x*f) = v_sin(x*f)
    rev = rev - floorf(rev);
    float val = (s < 16) ? __builtin_amdgcn_sinf(rev) : __builtin_amdgcn_cosf(rev);
    int cb = f * 2;
    *(unsigned short*)(Ha + r * 256 + (cb ^ ((r & 7) << 4))) = f2bf(val);
  }
  // ---- stage: alpha(tau) interp + zero pad (cols 96..127) ----
  if (tid < 64) {
    int i = row0 + tid;
    float tv = tauv[i];
    const float dtau = 1.0f / 100.0f;
    int idx = (int)floorf(tv / dtau);
    idx = min(max(idx, 0), 99);
    float ratio = (tv - (float)idx * dtau) / dtau;
#pragma unroll
    for (int j = 0; j < 10; j++) {
      float a0 = traj[idx * 10 + j], a1 = traj[idx * 10 + 10 + j];
      float al = fmaf(ratio, a1 - a0, a0);
      int cb = (96 + j) * 2;
      *(unsigned short*)(Ha + tid * 256 + (cb ^ ((tid & 7) << 4))) = f2bf(al);
    }
#pragma unroll
    for (int j = 106; j < 128; j++) {
      int cb = j * 2;
      *(unsigned short*)(Ha + tid * 256 + (cb ^ ((tid & 7) << 4))) = 0;
    }
  }
  __syncthreads();

  layer<4, 256, true>(Ha, pw0, db0, Hb, wave, lane);    // 106(pad128) -> 512
  __syncthreads();
  layer<16, 1024, true>(Hb, pw1, db1, Ha, wave, lane);  // 512 -> 512
  __syncthreads();
  layer<16, 1024, true>(Ha, pw2, db2, Hb, wave, lane);  // 512 -> 512
  __syncthreads();

  // ---- L3: 512 -> 1 via MFMA, waves 0..3 each own a 16-row m-tile ----
  float* ubuf = (float*)Ha;
  if (wave < 4) {
    f32x4 acc = {0.f, 0.f, 0.f, 0.f};
#pragma unroll
    for (int kc = 0; kc < 16; kc++) {
      int arow = wave * 16 + (lane & 15);
      int acb = kc * 64 + ((lane >> 4) << 4);
      bf16x8 af = *(const bf16x8*)(Hb + arow * 1024 + (acb ^ ((arow & 7) << 4)));
      bf16x8 bfv = *(const bf16x8*)(pw3 + (kc * 64 + lane) * 8);
      acc = __builtin_amdgcn_mfma_f32_16x16x32_bf16(af, bfv, acc, 0, 0, 0);
    }
    if ((lane & 15) == 0) {
#pragma unroll
      for (int r = 0; r < 4; r++) {
        int rr = wave * 16 + ((lane >> 4) << 2) + r;
        ubuf[rr] = acc[r];
      }
    }
  }
  __syncthreads();

  // ---- epilogue: out = lx + tau * (u + b3) ----
  if (tid < 64) {
    int i = row0 + tid;
    float x0 = x[i * 3], x1 = x[i * 3 + 1];
    float tv = tauv[i];
    float u = ubuf[tid] + db3[0];
    out[i] = sqrtf(x0 * x0 + x1 * x1) - 0.25f + tv * u;
  }
}

// ---------------- launch ----------------
extern "C" void kernel_launch(void* const* d_in, const int* in_sizes, int n_in,
                              void* d_out, int out_size, void* d_ws, size_t ws_size,
                              hipStream_t stream) {
  const float* x    = (const float*)d_in[0];
  const float* tauv = (const float*)d_in[1];
  const float* dw0  = (const float*)d_in[2];
  const float* db0  = (const float*)d_in[3];
  const float* dw1  = (const float*)d_in[4];
  const float* db1  = (const float*)d_in[5];
  const float* dw2  = (const float*)d_in[6];
  const float* db2  = (const float*)d_in[7];
  const float* dw3  = (const float*)d_in[8];
  const float* db3  = (const float*)d_in[9];
  const float* pnw0 = (const float*)d_in[10];
  const float* pnb0 = (const float*)d_in[11];
  const float* pnw1 = (const float*)d_in[12];
  const float* pnb1 = (const float*)d_in[13];
  const float* pnw2 = (const float*)d_in[14];
  const float* pnb2 = (const float*)d_in[15];
  float* out = (float*)d_out;

  unsigned short* pw0 = (unsigned short*)d_ws;
  unsigned short* pw1 = pw0 + 128 * 512;
  unsigned short* pw2 = pw1 + 512 * 512;
  unsigned short* pw3 = pw2 + 512 * 512;
  float* traj = (float*)(pw3 + 512 * 16);

  pack_kernel<<<(128 * 512) / 256, 256, 0, stream>>>(dw0, pw0, 106, 512, 4, 128 * 512);
  pack_kernel<<<(512 * 512) / 256, 256, 0, stream>>>(dw1, pw1, 512, 512, 16, 512 * 512);
  pack_kernel<<<(512 * 512) / 256, 256, 0, stream>>>(dw2, pw2, 512, 512, 16, 512 * 512);
  pack_kernel<<<(512 * 16) / 256, 256, 0, stream>>>(dw3, pw3, 512, 1, 16, 512 * 16);
  traj_kernel<<<1, 128, 0, stream>>>(pnw0, pnb0, pnw1, pnb1, pnw2, pnb2, traj);
  decoder_kernel<<<B_TOTAL / MTILE, 512, 0, stream>>>(x, tauv, pw0, db0, pw1, db1,
                                                      pw2, db2, pw3, db3, traj, out);
}